// Round 7
// baseline (518.251 us; speedup 1.0000x reference)
//
#include <hip/hip_runtime.h>
#include <hip/hip_bf16.h>

// SelfAttention2D: B=4, C=256, H=W=64, N=4096, Cqk=32.
// Round 7: R4's verified 64-row attn structure, slimmed to fit 2 blocks/CU
// (16 waves = 4/SIMD): V prefetch dropped (JIT V at step top, used after
// S+exp ~200cyc later), pu lifetime per-rt, __launch_bounds__(512,4).
// Prep = R4's 3-kernel path (best measured). Session accounting: harness
// fixed overhead ~85us; attn is the lever (R4 attn=94us @ 1 block/CU, 44% stall).

typedef __attribute__((ext_vector_type(8))) short s8v;  // 8 bf16 (MFMA A/B frag)
typedef __attribute__((ext_vector_type(4))) float f4v;  // MFMA C/D frag

#define NPIX 4096
#define CIN 256
#define DQK 32

#if __has_builtin(__builtin_amdgcn_exp2f)
#define EXP2(x) __builtin_amdgcn_exp2f(x)
#else
#define EXP2(x) exp2f(x)
#endif

static __device__ __forceinline__ unsigned short f2bf(float f) {
    union { float f; unsigned int u; } v; v.f = f;
    unsigned int r = v.u + 0x7FFF + ((v.u >> 16) & 1);   // RTNE
    return (unsigned short)(r >> 16);
}
static __device__ __forceinline__ unsigned int fbits(float f) {
    union { float f; unsigned int u; } v; v.f = f; return v.u;
}

// ---------------------------------------------------------------------------
// Kernel 1: pack Wq/Wk/Wv -> bf16 Wall[320][256], biases -> fp32 ball[320].
__global__ void wcast_kernel(const float* __restrict__ Wq, const float* __restrict__ bq,
                             const float* __restrict__ Wk, const float* __restrict__ bk,
                             const float* __restrict__ Wv, const float* __restrict__ bv,
                             unsigned short* __restrict__ Wall, float* __restrict__ ball) {
    int row = blockIdx.x;
    int t = threadIdx.x;
    const float* src; const float* bsrc;
    if (row < 32)       { src = Wq + row * 256;        bsrc = bq + row; }
    else if (row < 64)  { src = Wk + (row - 32) * 256; bsrc = bk + (row - 32); }
    else                { src = Wv + (row - 64) * 256; bsrc = bv + (row - 64); }
    Wall[row * 256 + t] = f2bf(src[t]);
    if (t == 0) ball[row] = bsrc[0];
}

// ---------------------------------------------------------------------------
// Kernel 2: x[b][c][n] fp32 -> xT[b][n][c] bf16 (64x64 LDS tile transpose).
__global__ void tcast_kernel(const float* __restrict__ x, unsigned short* __restrict__ xT) {
    __shared__ unsigned short tile[64][65];
    int bidx = blockIdx.x;
    int b    = bidx >> 8;
    int cblk = (bidx >> 6) & 3;
    int nblk = bidx & 63;
    int t = threadIdx.x;
    int c0 = cblk * 64, n0 = nblk * 64;
    const float* xb = x + (size_t)b * CIN * NPIX;
    #pragma unroll
    for (int p = 0; p < 4; p++) {
        int cl = p * 16 + (t >> 4);
        int nl = (t & 15) * 4;
        float4 v = *(const float4*)(xb + (size_t)(c0 + cl) * NPIX + n0 + nl);
        tile[cl][nl + 0] = f2bf(v.x);
        tile[cl][nl + 1] = f2bf(v.y);
        tile[cl][nl + 2] = f2bf(v.z);
        tile[cl][nl + 3] = f2bf(v.w);
    }
    __syncthreads();
    unsigned short* xTb = xT + (size_t)b * NPIX * CIN;
    #pragma unroll
    for (int p = 0; p < 4; p++) {
        int nl = p * 16 + (t >> 4);
        int cl = (t & 15) * 4;
        ushort4 wv;
        wv.x = tile[cl + 0][nl];
        wv.y = tile[cl + 1][nl];
        wv.z = tile[cl + 2][nl];
        wv.w = tile[cl + 3][nl];
        *(ushort4*)(xTb + (size_t)(n0 + nl) * CIN + c0 + cl) = wv;
    }
}

// ---------------------------------------------------------------------------
// Kernel 3: projection GEMM (R4-verified). grid = 256, 4 waves x 16 n-rows.
__global__ __launch_bounds__(256)
void proj_kernel(const unsigned short* __restrict__ xT,
                 const unsigned short* __restrict__ Wall,
                 const float* __restrict__ ball,
                 unsigned short* __restrict__ Q,
                 unsigned short* __restrict__ Kp,
                 unsigned short* __restrict__ Vt) {
    int idx  = blockIdx.x;
    int b    = (idx & 7) >> 1;
    int nblk = ((idx >> 3) << 1) | (idx & 1);
    int w    = threadIdx.x >> 6;
    int lane = threadIdx.x & 63;
    int l16 = lane & 15, quad = lane >> 4;
    int n0 = nblk * 64 + w * 16;

    const unsigned short* brow = xT + (size_t)(b * NPIX + n0 + l16) * CIN + quad * 8;
    s8v bfr[8];
    #pragma unroll
    for (int kk = 0; kk < 8; kk++) bfr[kk] = *(const s8v*)(brow + kk * 32);

    #pragma unroll
    for (int p = 0; p < 10; p++) {
        const unsigned short* w0 = Wall + (size_t)(2 * p * 16 + l16) * CIN + quad * 8;
        const unsigned short* w1 = w0 + 16 * CIN;
        f4v a0 = {0.f, 0.f, 0.f, 0.f}, a1 = {0.f, 0.f, 0.f, 0.f};
        if (p < 2) {  // Q/K: A=xT(rows=n), B=W(cols=oc)
            #pragma unroll
            for (int kk = 0; kk < 8; kk++) {
                a0 = __builtin_amdgcn_mfma_f32_16x16x32_bf16(bfr[kk], *(const s8v*)(w0 + kk * 32), a0, 0, 0, 0);
                a1 = __builtin_amdgcn_mfma_f32_16x16x32_bf16(bfr[kk], *(const s8v*)(w1 + kk * 32), a1, 0, 0, 0);
            }
        } else {      // V: A=W(rows=ch), B=xT(cols=n)
            #pragma unroll
            for (int kk = 0; kk < 8; kk++) {
                a0 = __builtin_amdgcn_mfma_f32_16x16x32_bf16(*(const s8v*)(w0 + kk * 32), bfr[kk], a0, 0, 0, 0);
                a1 = __builtin_amdgcn_mfma_f32_16x16x32_bf16(*(const s8v*)(w1 + kk * 32), bfr[kk], a1, 0, 0, 0);
            }
        }
        #pragma unroll
        for (int half = 0; half < 2; half++) {
            int ob = 2 * p + half;
            f4v acc = half ? a1 : a0;
            if (ob < 2) {            // Q: lane l16 = oc, reg r -> n-sub
                int oc = ob * 16 + l16;
                float bias = ball[oc];
                #pragma unroll
                for (int r = 0; r < 4; r++) {
                    int n = n0 + quad * 4 + r;
                    Q[(size_t)(b * NPIX + n) * DQK + oc] =
                        f2bf((acc[r] + bias) * 1.44269504f);
                }
            } else if (ob < 4) {     // K~: permuted row sigma^-1(n)
                int oc = (ob - 2) * 16 + l16;
                float bias = ball[32 + oc];
                #pragma unroll
                for (int r = 0; r < 4; r++) {
                    int n = n0 + quad * 4 + r;
                    int pn = (n & ~31) | (((n >> 2) & 1) << 4) | (((n >> 3) & 3) << 2) | (n & 3);
                    Kp[(size_t)(b * NPIX + pn) * DQK + oc] = f2bf(acc[r] + bias);
                }
            } else {                 // V: lane l16 = n, reg r -> ch-sub
                int n = n0 + l16;
                #pragma unroll
                for (int r = 0; r < 4; r++) {
                    int ch = (ob - 4) * 16 + quad * 4 + r;
                    Vt[((size_t)b * CIN + ch) * NPIX + n] = f2bf(acc[r] + ball[64 + ch]);
                }
            }
        }
    }
}

// ---------------------------------------------------------------------------
// Kernel 4: flash attention. 64 q-rows/block, grid 256, 8 waves = kh2 x cs4,
// 2 blocks/CU target (<=128 unified regs). V JIT (loaded at step top, used
// after S+exp); K depth-1 prefetch; pu lifetime limited to one rt.
#define ATTN_STEP(KC0, KC1, KN0, KN1, NKV_NEXT, NKV_CUR)                        \
    {                                                                           \
        s8v Vc[4];                                                              \
        _Pragma("unroll")                                                       \
        for (int ct = 0; ct < 4; ct++)                                          \
            Vc[ct] = *(const s8v*)(vbase + ct * 16 * NPIX + (NKV_CUR));         \
        KN0 = *(const s8v*)(kbase + (NKV_NEXT) * DQK);                          \
        KN1 = *(const s8v*)(kbase + ((NKV_NEXT) + 16) * DQK);                   \
        _Pragma("unroll")                                                       \
        for (int rt = 0; rt < 4; rt++) {                                        \
            f4v s0 = {0.f, 0.f, 0.f, 0.f}, s1 = {0.f, 0.f, 0.f, 0.f};           \
            s0 = __builtin_amdgcn_mfma_f32_16x16x32_bf16(KC0, qf[rt], s0, 0, 0, 0); \
            s1 = __builtin_amdgcn_mfma_f32_16x16x32_bf16(KC1, qf[rt], s1, 0, 0, 0); \
            float p00 = EXP2(s0[0]), p01 = EXP2(s0[1]);                         \
            float p02 = EXP2(s0[2]), p03 = EXP2(s0[3]);                         \
            float p10 = EXP2(s1[0]), p11 = EXP2(s1[1]);                         \
            float p12 = EXP2(s1[2]), p13 = EXP2(s1[3]);                         \
            lsum[rt] += ((p00 + p01) + (p02 + p03)) + ((p10 + p11) + (p12 + p13)); \
            union { uint4 u; s8v v; } pp;                                       \
            pp.u.x = __builtin_amdgcn_perm(fbits(p01), fbits(p00), 0x07060302); \
            pp.u.y = __builtin_amdgcn_perm(fbits(p03), fbits(p02), 0x07060302); \
            pp.u.z = __builtin_amdgcn_perm(fbits(p11), fbits(p10), 0x07060302); \
            pp.u.w = __builtin_amdgcn_perm(fbits(p13), fbits(p12), 0x07060302); \
            _Pragma("unroll")                                                   \
            for (int ct = 0; ct < 4; ct++)                                      \
                O[rt][ct] = __builtin_amdgcn_mfma_f32_16x16x32_bf16(Vc[ct], pp.v, O[rt][ct], 0, 0, 0); \
        }                                                                       \
    }

__global__ __launch_bounds__(512, 4)
void attn_kernel(const unsigned short* __restrict__ Q,
                 const unsigned short* __restrict__ Kp,
                 const unsigned short* __restrict__ Vt,
                 const float* __restrict__ gamma,
                 float* __restrict__ out) {
    __shared__ float ldsO[4][64][68];   // kh=1 partial: [cs][lane][16 f4v +pad]
    __shared__ float ldsL[4][16];       // kh=1 row-sums per (rt, l16)

    int idx = blockIdx.x;
    int b      = (idx & 7) >> 1;                    // batch -> XCD pair
    int rowblk = ((idx >> 3) << 1) | (idx & 1);

    int lane = threadIdx.x & 63;
    int w    = threadIdx.x >> 6;
    int l16 = lane & 15, quad = lane >> 4;
    int kh = w >> 2;     // key-half 0..1
    int cs = w & 3;      // 64-ch slice 0..3

    const unsigned short* Kb = Kp + (size_t)b * NPIX * DQK;
    const unsigned short* Vb = Vt + (size_t)b * CIN * NPIX;

    int rowbase = rowblk * 64;
    s8v qf[4];
    #pragma unroll
    for (int rt = 0; rt < 4; rt++)
        qf[rt] = *(const s8v*)(Q + (size_t)(b * NPIX + rowbase + rt * 16 + l16) * DQK + quad * 8);

    const unsigned short* kbase = Kb + (32 * kh + l16) * DQK + quad * 8;
    const unsigned short* vbase = Vb + (size_t)(cs * 64 + l16) * NPIX + 32 * kh + quad * 8;

    f4v O[4][4];
    #pragma unroll
    for (int rt = 0; rt < 4; rt++)
        #pragma unroll
        for (int ct = 0; ct < 4; ct++) O[rt][ct] = (f4v){0.f, 0.f, 0.f, 0.f};
    float lsum[4] = {0.f, 0.f, 0.f, 0.f};

    s8v Kc0, Kc1, Kn0, Kn1;
    Kc0 = *(const s8v*)(kbase);
    Kc1 = *(const s8v*)(kbase + 16 * DQK);

    for (int kv2 = 0; kv2 < NPIX; kv2 += 128) {
        ATTN_STEP(Kc0, Kc1, Kn0, Kn1, kv2 + 64, kv2);
        ATTN_STEP(Kn0, Kn1, Kc0, Kc1, (kv2 + 128) & (NPIX - 1), kv2 + 64);
    }

    // row-sums for this key-half (reduce over quads; all lanes get value)
    #pragma unroll
    for (int rt = 0; rt < 4; rt++) {
        lsum[rt] += __shfl_xor(lsum[rt], 16);
        lsum[rt] += __shfl_xor(lsum[rt], 32);
    }

    if (kh == 1) {
        #pragma unroll
        for (int rt = 0; rt < 4; rt++)
            #pragma unroll
            for (int ct = 0; ct < 4; ct++)
                *(f4v*)&ldsO[cs][lane][(rt * 4 + ct) * 4] = O[rt][ct];
        if (cs == 0 && quad == 0) {
            #pragma unroll
            for (int rt = 0; rt < 4; rt++) ldsL[rt][l16] = lsum[rt];
        }
    }
    __syncthreads();

    if (kh == 0) {
        float g = gamma[0];
        float rinv[4];
        #pragma unroll
        for (int rt = 0; rt < 4; rt++)
            rinv[rt] = g / (lsum[rt] + ldsL[rt][l16]);
        #pragma unroll
        for (int rt = 0; rt < 4; rt++) {
            #pragma unroll
            for (int ct = 0; ct < 4; ct++) {
                f4v o2 = *(const f4v*)&ldsO[cs][lane][(rt * 4 + ct) * 4];
                #pragma unroll
                for (int r = 0; r < 4; r++) {
                    int ch = cs * 64 + ct * 16 + quad * 4 + r;
                    out[((size_t)b * CIN + ch) * NPIX + rowbase + rt * 16 + l16] =
                        (O[rt][ct][r] + o2[r]) * rinv[rt];
                }
            }
        }
    }
}

// ---------------------------------------------------------------------------
extern "C" void kernel_launch(void* const* d_in, const int* in_sizes, int n_in,
                              void* d_out, int out_size, void* d_ws, size_t ws_size,
                              hipStream_t stream) {
    const float* x     = (const float*)d_in[0];
    const float* Wq    = (const float*)d_in[1];
    const float* bq    = (const float*)d_in[2];
    const float* Wk    = (const float*)d_in[3];
    const float* bk    = (const float*)d_in[4];
    const float* Wv    = (const float*)d_in[5];
    const float* bv    = (const float*)d_in[6];
    const float* gamma = (const float*)d_in[7];
    float* out = (float*)d_out;

    char* p = (char*)d_ws;
    unsigned short* xT   = (unsigned short*)p; p += (size_t)4 * NPIX * CIN * 2;   // 8 MB
    unsigned short* Qb   = (unsigned short*)p; p += (size_t)4 * NPIX * DQK * 2;   // 1 MB
    unsigned short* Kb   = (unsigned short*)p; p += (size_t)4 * NPIX * DQK * 2;   // 1 MB
    unsigned short* Vt   = (unsigned short*)p; p += (size_t)4 * CIN * NPIX * 2;   // 8 MB
    unsigned short* Wall = (unsigned short*)p; p += (size_t)320 * 256 * 2;
    float*          ball = (float*)p;          p += (size_t)320 * 4;

    wcast_kernel<<<320, 256, 0, stream>>>(Wq, bq, Wk, bk, Wv, bv, Wall, ball);
    tcast_kernel<<<1024, 256, 0, stream>>>(x, xT);
    proj_kernel<<<256, 256, 0, stream>>>(xT, Wall, ball, Qb, Kb, Vt);
    attn_kernel<<<256, 512, 0, stream>>>(Qb, Kb, Vt, gamma, out);
}

// Round 8
// 184.981 us; speedup vs baseline: 2.8016x; 2.8016x over previous
//
#include <hip/hip_runtime.h>
#include <hip/hip_bf16.h>

// SelfAttention2D: B=4, C=256, H=W=64, N=4096, Cqk=32.
// Round 8: S/exp dedup via LDS P-sharing with DRAIN-FREE barriers.
//  - 8 waves = 2 kh x 4 j. Wave (kh,j): S+exp for row-tile j ONLY (8 exp vs
//    32), P frag -> LDS (b128, swizzled, bank-balanced), raw
//    "s_waitcnt lgkmcnt(0); s_barrier" (global prefetch stays in flight!),
//    read 4 rt frags, PV for ch slice [j*64,+64).
//  - K sigma-permutation keeps P in B-frag key order (verified R3-R7).
//  - kh O-combine at end; epilogue LDS aliases the P buffer (one real
//    __syncthreads protects the alias).
//  - NO min-waves launch bound (R5/R7 lesson: forcing below ~184 unified
//    regs spills accumulators to scratch: FETCH 400MB+ signature).

typedef __attribute__((ext_vector_type(8))) short s8v;  // 8 bf16 (MFMA A/B frag)
typedef __attribute__((ext_vector_type(4))) float f4v;  // MFMA C/D frag

#define NPIX 4096
#define CIN 256
#define DQK 32

#if __has_builtin(__builtin_amdgcn_exp2f)
#define EXP2(x) __builtin_amdgcn_exp2f(x)
#else
#define EXP2(x) exp2f(x)
#endif

static __device__ __forceinline__ unsigned short f2bf(float f) {
    union { float f; unsigned int u; } v; v.f = f;
    unsigned int r = v.u + 0x7FFF + ((v.u >> 16) & 1);   // RTNE
    return (unsigned short)(r >> 16);
}
static __device__ __forceinline__ unsigned int fbits(float f) {
    union { float f; unsigned int u; } v; v.f = f; return v.u;
}

// ---------------------------------------------------------------------------
// Kernel 1: pack Wq/Wk/Wv -> bf16 Wall[320][256], biases -> fp32 ball[320].
__global__ void wcast_kernel(const float* __restrict__ Wq, const float* __restrict__ bq,
                             const float* __restrict__ Wk, const float* __restrict__ bk,
                             const float* __restrict__ Wv, const float* __restrict__ bv,
                             unsigned short* __restrict__ Wall, float* __restrict__ ball) {
    int row = blockIdx.x;
    int t = threadIdx.x;
    const float* src; const float* bsrc;
    if (row < 32)       { src = Wq + row * 256;        bsrc = bq + row; }
    else if (row < 64)  { src = Wk + (row - 32) * 256; bsrc = bk + (row - 32); }
    else                { src = Wv + (row - 64) * 256; bsrc = bv + (row - 64); }
    Wall[row * 256 + t] = f2bf(src[t]);
    if (t == 0) ball[row] = bsrc[0];
}

// ---------------------------------------------------------------------------
// Kernel 2: x[b][c][n] fp32 -> xT[b][n][c] bf16 (64x64 LDS tile transpose).
__global__ void tcast_kernel(const float* __restrict__ x, unsigned short* __restrict__ xT) {
    __shared__ unsigned short tile[64][65];
    int bidx = blockIdx.x;
    int b    = bidx >> 8;
    int cblk = (bidx >> 6) & 3;
    int nblk = bidx & 63;
    int t = threadIdx.x;
    int c0 = cblk * 64, n0 = nblk * 64;
    const float* xb = x + (size_t)b * CIN * NPIX;
    #pragma unroll
    for (int p = 0; p < 4; p++) {
        int cl = p * 16 + (t >> 4);
        int nl = (t & 15) * 4;
        float4 v = *(const float4*)(xb + (size_t)(c0 + cl) * NPIX + n0 + nl);
        tile[cl][nl + 0] = f2bf(v.x);
        tile[cl][nl + 1] = f2bf(v.y);
        tile[cl][nl + 2] = f2bf(v.z);
        tile[cl][nl + 3] = f2bf(v.w);
    }
    __syncthreads();
    unsigned short* xTb = xT + (size_t)b * NPIX * CIN;
    #pragma unroll
    for (int p = 0; p < 4; p++) {
        int nl = p * 16 + (t >> 4);
        int cl = (t & 15) * 4;
        ushort4 wv;
        wv.x = tile[cl + 0][nl];
        wv.y = tile[cl + 1][nl];
        wv.z = tile[cl + 2][nl];
        wv.w = tile[cl + 3][nl];
        *(ushort4*)(xTb + (size_t)(n0 + nl) * CIN + c0 + cl) = wv;
    }
}

// ---------------------------------------------------------------------------
// Kernel 3: projection GEMM (R4-verified). grid = 256, 4 waves x 16 n-rows.
__global__ __launch_bounds__(256)
void proj_kernel(const unsigned short* __restrict__ xT,
                 const unsigned short* __restrict__ Wall,
                 const float* __restrict__ ball,
                 unsigned short* __restrict__ Q,
                 unsigned short* __restrict__ Kp,
                 unsigned short* __restrict__ Vt) {
    int idx  = blockIdx.x;
    int b    = (idx & 7) >> 1;
    int nblk = ((idx >> 3) << 1) | (idx & 1);
    int w    = threadIdx.x >> 6;
    int lane = threadIdx.x & 63;
    int l16 = lane & 15, quad = lane >> 4;
    int n0 = nblk * 64 + w * 16;

    const unsigned short* brow = xT + (size_t)(b * NPIX + n0 + l16) * CIN + quad * 8;
    s8v bfr[8];
    #pragma unroll
    for (int kk = 0; kk < 8; kk++) bfr[kk] = *(const s8v*)(brow + kk * 32);

    #pragma unroll
    for (int p = 0; p < 10; p++) {
        const unsigned short* w0 = Wall + (size_t)(2 * p * 16 + l16) * CIN + quad * 8;
        const unsigned short* w1 = w0 + 16 * CIN;
        f4v a0 = {0.f, 0.f, 0.f, 0.f}, a1 = {0.f, 0.f, 0.f, 0.f};
        if (p < 2) {  // Q/K: A=xT(rows=n), B=W(cols=oc)
            #pragma unroll
            for (int kk = 0; kk < 8; kk++) {
                a0 = __builtin_amdgcn_mfma_f32_16x16x32_bf16(bfr[kk], *(const s8v*)(w0 + kk * 32), a0, 0, 0, 0);
                a1 = __builtin_amdgcn_mfma_f32_16x16x32_bf16(bfr[kk], *(const s8v*)(w1 + kk * 32), a1, 0, 0, 0);
            }
        } else {      // V: A=W(rows=ch), B=xT(cols=n)
            #pragma unroll
            for (int kk = 0; kk < 8; kk++) {
                a0 = __builtin_amdgcn_mfma_f32_16x16x32_bf16(*(const s8v*)(w0 + kk * 32), bfr[kk], a0, 0, 0, 0);
                a1 = __builtin_amdgcn_mfma_f32_16x16x32_bf16(*(const s8v*)(w1 + kk * 32), bfr[kk], a1, 0, 0, 0);
            }
        }
        #pragma unroll
        for (int half = 0; half < 2; half++) {
            int ob = 2 * p + half;
            f4v acc = half ? a1 : a0;
            if (ob < 2) {            // Q: lane l16 = oc, reg r -> n-sub
                int oc = ob * 16 + l16;
                float bias = ball[oc];
                #pragma unroll
                for (int r = 0; r < 4; r++) {
                    int n = n0 + quad * 4 + r;
                    Q[(size_t)(b * NPIX + n) * DQK + oc] =
                        f2bf((acc[r] + bias) * 1.44269504f);
                }
            } else if (ob < 4) {     // K~: permuted row sigma^-1(n)
                int oc = (ob - 2) * 16 + l16;
                float bias = ball[32 + oc];
                #pragma unroll
                for (int r = 0; r < 4; r++) {
                    int n = n0 + quad * 4 + r;
                    int pn = (n & ~31) | (((n >> 2) & 1) << 4) | (((n >> 3) & 3) << 2) | (n & 3);
                    Kp[(size_t)(b * NPIX + pn) * DQK + oc] = f2bf(acc[r] + bias);
                }
            } else {                 // V: lane l16 = n, reg r -> ch-sub
                int n = n0 + l16;
                #pragma unroll
                for (int r = 0; r < 4; r++) {
                    int ch = (ob - 4) * 16 + quad * 4 + r;
                    Vt[((size_t)b * CIN + ch) * NPIX + n] = f2bf(acc[r] + ball[64 + ch]);
                }
            }
        }
    }
}

// ---------------------------------------------------------------------------
// Kernel 4: flash attention with P-sharing. 64 q-rows/block, grid 256,
// 512 threads = 8 waves: (kh = w>>2) x (cj = w&3).
// P LDS tile: [kh][buf][rt][16 rows][4 x 16B units], unit u at swizzled
// position u^(l16&3): bank-balanced (8 touches/bank = inherent minimum).
#define ATTN_STEP(BUF, KC0, KC1, VC, KN0, KN1, VN, NKV_NEXT)                    \
    {                                                                           \
        KN0 = *(const s8v*)(kbase + (NKV_NEXT) * DQK);                          \
        KN1 = *(const s8v*)(kbase + ((NKV_NEXT) + 16) * DQK);                   \
        _Pragma("unroll")                                                       \
        for (int ct = 0; ct < 4; ct++)                                          \
            VN[ct] = *(const s8v*)(vbase + ct * 16 * NPIX + (NKV_NEXT));        \
        f4v s0 = {0.f, 0.f, 0.f, 0.f}, s1 = {0.f, 0.f, 0.f, 0.f};               \
        s0 = __builtin_amdgcn_mfma_f32_16x16x32_bf16(KC0, qf, s0, 0, 0, 0);     \
        s1 = __builtin_amdgcn_mfma_f32_16x16x32_bf16(KC1, qf, s1, 0, 0, 0);     \
        float p00 = EXP2(s0[0]), p01 = EXP2(s0[1]);                             \
        float p02 = EXP2(s0[2]), p03 = EXP2(s0[3]);                             \
        float p10 = EXP2(s1[0]), p11 = EXP2(s1[1]);                             \
        float p12 = EXP2(s1[2]), p13 = EXP2(s1[3]);                             \
        lsum += ((p00 + p01) + (p02 + p03)) + ((p10 + p11) + (p12 + p13));      \
        union { uint4 u; s8v v; } pp;                                           \
        pp.u.x = __builtin_amdgcn_perm(fbits(p01), fbits(p00), 0x07060302);     \
        pp.u.y = __builtin_amdgcn_perm(fbits(p03), fbits(p02), 0x07060302);     \
        pp.u.z = __builtin_amdgcn_perm(fbits(p11), fbits(p10), 0x07060302);     \
        pp.u.w = __builtin_amdgcn_perm(fbits(p13), fbits(p12), 0x07060302);     \
        *(uint4*)(Pme + (BUF) * 1024) = pp.u;                                   \
        __asm__ __volatile__("s_waitcnt lgkmcnt(0)\n\ts_barrier" ::: "memory"); \
        s8v pa[4];                                                              \
        _Pragma("unroll")                                                       \
        for (int rt = 0; rt < 4; rt++) {                                        \
            if (rt == cj) pa[rt] = pp.v;                                        \
            else          pa[rt] = *(const s8v*)(Pkh + (BUF) * 1024 + rt * 256);\
        }                                                                       \
        _Pragma("unroll")                                                       \
        for (int ct = 0; ct < 4; ct++)                                          \
            _Pragma("unroll")                                                   \
            for (int rt = 0; rt < 4; rt++)                                      \
                O[rt][ct] = __builtin_amdgcn_mfma_f32_16x16x32_bf16(VC[ct], pa[rt], O[rt][ct], 0, 0, 0); \
    }

__global__ __launch_bounds__(512)
void attn_kernel(const unsigned short* __restrict__ Q,
                 const unsigned short* __restrict__ Kp,
                 const unsigned short* __restrict__ Vt,
                 const float* __restrict__ gamma,
                 float* __restrict__ out) {
    // P region (loop): [kh 2][buf 2][rt 4][256 words] = 16 KB.
    // Epilogue (aliased, after a full __syncthreads): ldsO 69632 B + ldsL 512 B.
    __shared__ __align__(16) char smem[70144];

    int idx = blockIdx.x;
    int b      = (idx & 7) >> 1;                    // batch -> XCD pair
    int rowblk = ((idx >> 3) << 1) | (idx & 1);

    int lane = threadIdx.x & 63;
    int w    = threadIdx.x >> 6;
    int l16 = lane & 15, quad = lane >> 4;
    int kh = w >> 2;     // key-half 0..1
    int cj = w & 3;      // row-tile for S AND 64-ch slice for PV

    const unsigned short* Kb = Kp + (size_t)b * NPIX * DQK;
    const unsigned short* Vb = Vt + (size_t)b * CIN * NPIX;

    int rowbase = rowblk * 64;
    // Q B-frag for own row-tile only (log2e pre-folded at projection)
    const s8v qf = *(const s8v*)(Q + (size_t)(b * NPIX + rowbase + cj * 16 + l16) * DQK + quad * 8);

    const unsigned short* kbase = Kb + (32 * kh + l16) * DQK + quad * 8;
    const unsigned short* vbase = Vb + (size_t)(cj * 64 + l16) * NPIX + 32 * kh + quad * 8;

    // LDS P pointers (word units). Swizzled unit position: u^(l16&3).
    int lswz = l16 * 16 + ((quad ^ (l16 & 3)) << 2);
    unsigned int* Pkh = (unsigned int*)smem + kh * 2048 + lswz;  // + buf*1024 + rt*256
    unsigned int* Pme = Pkh + cj * 256;

    f4v O[4][4];
    #pragma unroll
    for (int rt = 0; rt < 4; rt++)
        #pragma unroll
        for (int ct = 0; ct < 4; ct++) O[rt][ct] = (f4v){0.f, 0.f, 0.f, 0.f};
    float lsum = 0.f;

    s8v Kc0, Kc1, Kn0, Kn1, Vc[4], Vn[4];
    Kc0 = *(const s8v*)(kbase);
    Kc1 = *(const s8v*)(kbase + 16 * DQK);
    #pragma unroll
    for (int ct = 0; ct < 4; ct++)
        Vc[ct] = *(const s8v*)(vbase + ct * 16 * NPIX);

    for (int kv2 = 0; kv2 < NPIX; kv2 += 128) {
        ATTN_STEP(0, Kc0, Kc1, Vc, Kn0, Kn1, Vn, kv2 + 64);
        ATTN_STEP(1, Kn0, Kn1, Vn, Kc0, Kc1, Vc, (kv2 + 128) & (NPIX - 1));
    }

    // full row-sum for (rt=cj, kh): reduce over quads
    lsum += __shfl_xor(lsum, 16);
    lsum += __shfl_xor(lsum, 32);

    __syncthreads();   // drain all P reads; safe to alias smem as epilogue bufs

    float (*ldsO)[64][68] = (float (*)[64][68])smem;          // [cj][lane][16 f4v + pad]
    float* ldsL = (float*)(smem + 69632);                     // [kh][rt][16]

    if (quad == 0) ldsL[kh * 64 + cj * 16 + l16] = lsum;
    if (kh == 1) {
        #pragma unroll
        for (int rt = 0; rt < 4; rt++)
            #pragma unroll
            for (int ct = 0; ct < 4; ct++)
                *(f4v*)&ldsO[cj][lane][(rt * 4 + ct) * 4] = O[rt][ct];
    }
    __syncthreads();

    if (kh == 0) {
        float g = gamma[0];
        float rinv[4];
        #pragma unroll
        for (int rt = 0; rt < 4; rt++)
            rinv[rt] = g / (ldsL[rt * 16 + l16] + ldsL[64 + rt * 16 + l16]);
        #pragma unroll
        for (int rt = 0; rt < 4; rt++) {
            #pragma unroll
            for (int ct = 0; ct < 4; ct++) {
                f4v o2 = *(const f4v*)&ldsO[cj][lane][(rt * 4 + ct) * 4];
                #pragma unroll
                for (int r = 0; r < 4; r++) {
                    int ch = cj * 64 + ct * 16 + quad * 4 + r;
                    out[((size_t)b * CIN + ch) * NPIX + rowbase + rt * 16 + l16] =
                        (O[rt][ct][r] + o2[r]) * rinv[rt];
                }
            }
        }
    }
}

// ---------------------------------------------------------------------------
extern "C" void kernel_launch(void* const* d_in, const int* in_sizes, int n_in,
                              void* d_out, int out_size, void* d_ws, size_t ws_size,
                              hipStream_t stream) {
    const float* x     = (const float*)d_in[0];
    const float* Wq    = (const float*)d_in[1];
    const float* bq    = (const float*)d_in[2];
    const float* Wk    = (const float*)d_in[3];
    const float* bk    = (const float*)d_in[4];
    const float* Wv    = (const float*)d_in[5];
    const float* bv    = (const float*)d_in[6];
    const float* gamma = (const float*)d_in[7];
    float* out = (float*)d_out;

    char* p = (char*)d_ws;
    unsigned short* xT   = (unsigned short*)p; p += (size_t)4 * NPIX * CIN * 2;   // 8 MB
    unsigned short* Qb   = (unsigned short*)p; p += (size_t)4 * NPIX * DQK * 2;   // 1 MB
    unsigned short* Kb   = (unsigned short*)p; p += (size_t)4 * NPIX * DQK * 2;   // 1 MB
    unsigned short* Vt   = (unsigned short*)p; p += (size_t)4 * CIN * NPIX * 2;   // 8 MB
    unsigned short* Wall = (unsigned short*)p; p += (size_t)320 * 256 * 2;
    float*          ball = (float*)p;          p += (size_t)320 * 4;

    wcast_kernel<<<320, 256, 0, stream>>>(Wq, bq, Wk, bk, Wv, bv, Wall, ball);
    tcast_kernel<<<1024, 256, 0, stream>>>(x, xT);
    proj_kernel<<<256, 256, 0, stream>>>(xT, Wall, ball, Qb, Kb, Vt);
    attn_kernel<<<256, 512, 0, stream>>>(Qb, Kb, Vt, gamma, out);
}

// Round 9
// 182.676 us; speedup vs baseline: 2.8370x; 1.0126x over previous
//
#include <hip/hip_runtime.h>
#include <hip/hip_bf16.h>

// SelfAttention2D: B=4, C=256, H=W=64, N=4096, Cqk=32.
// Round 9: R8's P-sharing flash attention with
//  (a) drain-free barrier: s_waitcnt lgkmcnt(0) via builtin (NO memory
//      clobber, NO vmcnt drain) + raw s_barrier -> global K/V prefetch
//      stays in flight across the barrier (the R8 inline-asm "memory"
//      clobber was forcing a per-step load drain);
//  (b) software-pipelined P: step s reads P_{s-1} (issued FIRST, latency
//      hidden under S/exp), writes P_s, does PV_{s-1}; double buffer is
//      race-free (reads of buf[x] finish before step-s barrier; next
//      write to buf[x] is at s+1);
//  (c) conflict-free P layout: 256B rows, unit (tile*4+quad)^(l16&7) ->
//      each 8-lane phase covers all 32 banks exactly once.
// No min-waves bound (R5/R7: capping below ~184 unified regs spills accs).

typedef __attribute__((ext_vector_type(8))) short s8v;  // 8 bf16 (MFMA A/B frag)
typedef __attribute__((ext_vector_type(4))) float f4v;  // MFMA C/D frag

#define NPIX 4096
#define CIN 256
#define DQK 32

#if __has_builtin(__builtin_amdgcn_exp2f)
#define EXP2(x) __builtin_amdgcn_exp2f(x)
#else
#define EXP2(x) exp2f(x)
#endif

// lgkmcnt(0), vmcnt=63 (untouched), expcnt=7 (untouched): 0xC07F
#if __has_builtin(__builtin_amdgcn_s_waitcnt)
#define LGKM0_BARRIER() { __builtin_amdgcn_s_waitcnt(0xC07F); __builtin_amdgcn_s_barrier(); }
#else
#define LGKM0_BARRIER() { __asm__ __volatile__("s_waitcnt lgkmcnt(0)\n\ts_barrier" ::: "memory"); }
#endif

static __device__ __forceinline__ unsigned short f2bf(float f) {
    union { float f; unsigned int u; } v; v.f = f;
    unsigned int r = v.u + 0x7FFF + ((v.u >> 16) & 1);   // RTNE
    return (unsigned short)(r >> 16);
}
static __device__ __forceinline__ unsigned int fbits(float f) {
    union { float f; unsigned int u; } v; v.f = f; return v.u;
}

// ---------------------------------------------------------------------------
// Kernel 1: pack Wq/Wk/Wv -> bf16 Wall[320][256], biases -> fp32 ball[320].
__global__ void wcast_kernel(const float* __restrict__ Wq, const float* __restrict__ bq,
                             const float* __restrict__ Wk, const float* __restrict__ bk,
                             const float* __restrict__ Wv, const float* __restrict__ bv,
                             unsigned short* __restrict__ Wall, float* __restrict__ ball) {
    int row = blockIdx.x;
    int t = threadIdx.x;
    const float* src; const float* bsrc;
    if (row < 32)       { src = Wq + row * 256;        bsrc = bq + row; }
    else if (row < 64)  { src = Wk + (row - 32) * 256; bsrc = bk + (row - 32); }
    else                { src = Wv + (row - 64) * 256; bsrc = bv + (row - 64); }
    Wall[row * 256 + t] = f2bf(src[t]);
    if (t == 0) ball[row] = bsrc[0];
}

// ---------------------------------------------------------------------------
// Kernel 2: x[b][c][n] fp32 -> xT[b][n][c] bf16 (64x64 LDS tile transpose).
__global__ void tcast_kernel(const float* __restrict__ x, unsigned short* __restrict__ xT) {
    __shared__ unsigned short tile[64][65];
    int bidx = blockIdx.x;
    int b    = bidx >> 8;
    int cblk = (bidx >> 6) & 3;
    int nblk = bidx & 63;
    int t = threadIdx.x;
    int c0 = cblk * 64, n0 = nblk * 64;
    const float* xb = x + (size_t)b * CIN * NPIX;
    #pragma unroll
    for (int p = 0; p < 4; p++) {
        int cl = p * 16 + (t >> 4);
        int nl = (t & 15) * 4;
        float4 v = *(const float4*)(xb + (size_t)(c0 + cl) * NPIX + n0 + nl);
        tile[cl][nl + 0] = f2bf(v.x);
        tile[cl][nl + 1] = f2bf(v.y);
        tile[cl][nl + 2] = f2bf(v.z);
        tile[cl][nl + 3] = f2bf(v.w);
    }
    __syncthreads();
    unsigned short* xTb = xT + (size_t)b * NPIX * CIN;
    #pragma unroll
    for (int p = 0; p < 4; p++) {
        int nl = p * 16 + (t >> 4);
        int cl = (t & 15) * 4;
        ushort4 wv;
        wv.x = tile[cl + 0][nl];
        wv.y = tile[cl + 1][nl];
        wv.z = tile[cl + 2][nl];
        wv.w = tile[cl + 3][nl];
        *(ushort4*)(xTb + (size_t)(n0 + nl) * CIN + c0 + cl) = wv;
    }
}

// ---------------------------------------------------------------------------
// Kernel 3: projection GEMM (R4-verified). grid = 256, 4 waves x 16 n-rows.
__global__ __launch_bounds__(256)
void proj_kernel(const unsigned short* __restrict__ xT,
                 const unsigned short* __restrict__ Wall,
                 const float* __restrict__ ball,
                 unsigned short* __restrict__ Q,
                 unsigned short* __restrict__ Kp,
                 unsigned short* __restrict__ Vt) {
    int idx  = blockIdx.x;
    int b    = (idx & 7) >> 1;
    int nblk = ((idx >> 3) << 1) | (idx & 1);
    int w    = threadIdx.x >> 6;
    int lane = threadIdx.x & 63;
    int l16 = lane & 15, quad = lane >> 4;
    int n0 = nblk * 64 + w * 16;

    const unsigned short* brow = xT + (size_t)(b * NPIX + n0 + l16) * CIN + quad * 8;
    s8v bfr[8];
    #pragma unroll
    for (int kk = 0; kk < 8; kk++) bfr[kk] = *(const s8v*)(brow + kk * 32);

    #pragma unroll
    for (int p = 0; p < 10; p++) {
        const unsigned short* w0 = Wall + (size_t)(2 * p * 16 + l16) * CIN + quad * 8;
        const unsigned short* w1 = w0 + 16 * CIN;
        f4v a0 = {0.f, 0.f, 0.f, 0.f}, a1 = {0.f, 0.f, 0.f, 0.f};
        if (p < 2) {  // Q/K: A=xT(rows=n), B=W(cols=oc)
            #pragma unroll
            for (int kk = 0; kk < 8; kk++) {
                a0 = __builtin_amdgcn_mfma_f32_16x16x32_bf16(bfr[kk], *(const s8v*)(w0 + kk * 32), a0, 0, 0, 0);
                a1 = __builtin_amdgcn_mfma_f32_16x16x32_bf16(bfr[kk], *(const s8v*)(w1 + kk * 32), a1, 0, 0, 0);
            }
        } else {      // V: A=W(rows=ch), B=xT(cols=n)
            #pragma unroll
            for (int kk = 0; kk < 8; kk++) {
                a0 = __builtin_amdgcn_mfma_f32_16x16x32_bf16(*(const s8v*)(w0 + kk * 32), bfr[kk], a0, 0, 0, 0);
                a1 = __builtin_amdgcn_mfma_f32_16x16x32_bf16(*(const s8v*)(w1 + kk * 32), bfr[kk], a1, 0, 0, 0);
            }
        }
        #pragma unroll
        for (int half = 0; half < 2; half++) {
            int ob = 2 * p + half;
            f4v acc = half ? a1 : a0;
            if (ob < 2) {            // Q: lane l16 = oc, reg r -> n-sub
                int oc = ob * 16 + l16;
                float bias = ball[oc];
                #pragma unroll
                for (int r = 0; r < 4; r++) {
                    int n = n0 + quad * 4 + r;
                    Q[(size_t)(b * NPIX + n) * DQK + oc] =
                        f2bf((acc[r] + bias) * 1.44269504f);
                }
            } else if (ob < 4) {     // K~: permuted row sigma^-1(n)
                int oc = (ob - 2) * 16 + l16;
                float bias = ball[32 + oc];
                #pragma unroll
                for (int r = 0; r < 4; r++) {
                    int n = n0 + quad * 4 + r;
                    int pn = (n & ~31) | (((n >> 2) & 1) << 4) | (((n >> 3) & 3) << 2) | (n & 3);
                    Kp[(size_t)(b * NPIX + pn) * DQK + oc] = f2bf(acc[r] + bias);
                }
            } else {                 // V: lane l16 = n, reg r -> ch-sub
                int n = n0 + l16;
                #pragma unroll
                for (int r = 0; r < 4; r++) {
                    int ch = (ob - 4) * 16 + quad * 4 + r;
                    Vt[((size_t)b * CIN + ch) * NPIX + n] = f2bf(acc[r] + ball[64 + ch]);
                }
            }
        }
    }
}

// ---------------------------------------------------------------------------
// Kernel 4: pipelined P-sharing flash attention. 64 q-rows/block, grid 256,
// 512 threads = 8 waves: (kh = w>>2) x (cj = w&3). 64 steps of 32 keys/wave.
// P LDS: [kh 2][buf 2][row 16][unit 16 x 16B], unit (tile*4+quad)^(l16&7).
#define ATTN_STEP(S, WB, KC0, KC1, VC, KN0, KN1, VN)                            \
    {                                                                           \
        const int kvn = ((S) + 1) & 63;                                         \
        KN0 = *(const s8v*)(kbase + (size_t)(kvn * 64) * DQK);                  \
        KN1 = *(const s8v*)(kbase + (size_t)(kvn * 64 + 16) * DQK);             \
        _Pragma("unroll")                                                       \
        for (int ct = 0; ct < 4; ct++)                                          \
            VN[ct] = *(const s8v*)(vbase + (size_t)ct * 16 * NPIX + (S) * 64);  \
        const unsigned int* rb = smemw + khw + (1 - (WB)) * 1024;               \
        s8v pa0 = (cj == 0) ? ppv : *(const s8v*)(rb + rdo0);                   \
        s8v pa1 = (cj == 1) ? ppv : *(const s8v*)(rb + rdo1);                   \
        s8v pa2 = (cj == 2) ? ppv : *(const s8v*)(rb + rdo2);                   \
        s8v pa3 = (cj == 3) ? ppv : *(const s8v*)(rb + rdo3);                   \
        f4v s0 = {0.f, 0.f, 0.f, 0.f}, s1 = {0.f, 0.f, 0.f, 0.f};               \
        s0 = __builtin_amdgcn_mfma_f32_16x16x32_bf16(KC0, qf, s0, 0, 0, 0);     \
        s1 = __builtin_amdgcn_mfma_f32_16x16x32_bf16(KC1, qf, s1, 0, 0, 0);     \
        float p00 = EXP2(s0[0]), p01 = EXP2(s0[1]);                             \
        float p02 = EXP2(s0[2]), p03 = EXP2(s0[3]);                             \
        float p10 = EXP2(s1[0]), p11 = EXP2(s1[1]);                             \
        float p12 = EXP2(s1[2]), p13 = EXP2(s1[3]);                             \
        lsum += ((p00 + p01) + (p02 + p03)) + ((p10 + p11) + (p12 + p13));      \
        union { uint4 u; s8v v; } pp;                                           \
        pp.u.x = __builtin_amdgcn_perm(fbits(p01), fbits(p00), 0x07060302);     \
        pp.u.y = __builtin_amdgcn_perm(fbits(p03), fbits(p02), 0x07060302);     \
        pp.u.z = __builtin_amdgcn_perm(fbits(p11), fbits(p10), 0x07060302);     \
        pp.u.w = __builtin_amdgcn_perm(fbits(p13), fbits(p12), 0x07060302);     \
        *(uint4*)(smemw + khw + (WB) * 1024 + wro) = pp.u;                      \
        _Pragma("unroll")                                                       \
        for (int ct = 0; ct < 4; ct++) {                                        \
            O[0][ct] = __builtin_amdgcn_mfma_f32_16x16x32_bf16(VC[ct], pa0, O[0][ct], 0, 0, 0); \
            O[1][ct] = __builtin_amdgcn_mfma_f32_16x16x32_bf16(VC[ct], pa1, O[1][ct], 0, 0, 0); \
            O[2][ct] = __builtin_amdgcn_mfma_f32_16x16x32_bf16(VC[ct], pa2, O[2][ct], 0, 0, 0); \
            O[3][ct] = __builtin_amdgcn_mfma_f32_16x16x32_bf16(VC[ct], pa3, O[3][ct], 0, 0, 0); \
        }                                                                       \
        LGKM0_BARRIER();                                                        \
        ppv = pp.v;                                                             \
    }

__global__ __launch_bounds__(512)
void attn_kernel(const unsigned short* __restrict__ Q,
                 const unsigned short* __restrict__ Kp,
                 const unsigned short* __restrict__ Vt,
                 const float* __restrict__ gamma,
                 float* __restrict__ out) {
    // P region (loop): 2kh x 2buf x 4KB = 16 KB at base.
    // Epilogue (aliased after full __syncthreads): ldsO 69632 B + ldsL 512 B.
    __shared__ __align__(16) char smem[70144];
    unsigned int* smemw = (unsigned int*)smem;

    int idx = blockIdx.x;
    int b      = (idx & 7) >> 1;                    // batch -> XCD pair
    int rowblk = ((idx >> 3) << 1) | (idx & 1);

    int lane = threadIdx.x & 63;
    int w    = threadIdx.x >> 6;
    int l16 = lane & 15, quad = lane >> 4;
    int kh = w >> 2;     // key-half 0..1
    int cj = w & 3;      // row-tile for S AND 64-ch slice for PV

    const unsigned short* Kb = Kp + (size_t)b * NPIX * DQK;
    const unsigned short* Vb = Vt + (size_t)b * CIN * NPIX;

    int rowbase = rowblk * 64;
    const s8v qf = *(const s8v*)(Q + (size_t)(b * NPIX + rowbase + cj * 16 + l16) * DQK + quad * 8);

    const unsigned short* kbase = Kb + (32 * kh + l16) * DQK + quad * 8;
    const unsigned short* vbase = Vb + (size_t)(cj * 64 + l16) * NPIX + 32 * kh + quad * 8;

    // LDS offsets (words): write own tile cj, read tiles rt.
    const int khw  = kh * 2048;
    const int wro  = l16 * 64 + (((cj * 4 + quad) ^ (l16 & 7)) << 2);
    const int rdo0 = l16 * 64 + (((0 * 4 + quad) ^ (l16 & 7)) << 2);
    const int rdo1 = l16 * 64 + (((1 * 4 + quad) ^ (l16 & 7)) << 2);
    const int rdo2 = l16 * 64 + (((2 * 4 + quad) ^ (l16 & 7)) << 2);
    const int rdo3 = l16 * 64 + (((3 * 4 + quad) ^ (l16 & 7)) << 2);

    f4v O[4][4];
    #pragma unroll
    for (int rt = 0; rt < 4; rt++)
        #pragma unroll
        for (int ct = 0; ct < 4; ct++) O[rt][ct] = (f4v){0.f, 0.f, 0.f, 0.f};
    float lsum = 0.f;
    s8v ppv;

    s8v Kc0, Kc1, Kn0, Kn1, Vc[4], Vn[4];
    Kc0 = *(const s8v*)(kbase);
    Kc1 = *(const s8v*)(kbase + 16 * DQK);

    // ---- step 0 (peeled: S only, write buf0, no PV) ----
    {
        Kn0 = *(const s8v*)(kbase + (size_t)64 * DQK);
        Kn1 = *(const s8v*)(kbase + (size_t)80 * DQK);
        #pragma unroll
        for (int ct = 0; ct < 4; ct++)
            Vc[ct] = *(const s8v*)(vbase + (size_t)ct * 16 * NPIX);   // V(0)
        f4v s0 = {0.f, 0.f, 0.f, 0.f}, s1 = {0.f, 0.f, 0.f, 0.f};
        s0 = __builtin_amdgcn_mfma_f32_16x16x32_bf16(Kc0, qf, s0, 0, 0, 0);
        s1 = __builtin_amdgcn_mfma_f32_16x16x32_bf16(Kc1, qf, s1, 0, 0, 0);
        float p00 = EXP2(s0[0]), p01 = EXP2(s0[1]);
        float p02 = EXP2(s0[2]), p03 = EXP2(s0[3]);
        float p10 = EXP2(s1[0]), p11 = EXP2(s1[1]);
        float p12 = EXP2(s1[2]), p13 = EXP2(s1[3]);
        lsum += ((p00 + p01) + (p02 + p03)) + ((p10 + p11) + (p12 + p13));
        union { uint4 u; s8v v; } pp;
        pp.u.x = __builtin_amdgcn_perm(fbits(p01), fbits(p00), 0x07060302);
        pp.u.y = __builtin_amdgcn_perm(fbits(p03), fbits(p02), 0x07060302);
        pp.u.z = __builtin_amdgcn_perm(fbits(p11), fbits(p10), 0x07060302);
        pp.u.w = __builtin_amdgcn_perm(fbits(p13), fbits(p12), 0x07060302);
        *(uint4*)(smemw + khw + 0 * 1024 + wro) = pp.u;
        LGKM0_BARRIER();
        ppv = pp.v;
    }

    // ---- steps 1..62 (31 unrolled pairs) ----
    for (int p = 0; p < 31; p++) {
        int s1i = 2 * p + 1;
        ATTN_STEP(s1i,     1, Kn0, Kn1, Vc, Kc0, Kc1, Vn);
        ATTN_STEP(s1i + 1, 0, Kc0, Kc1, Vn, Kn0, Kn1, Vc);
    }
    // ---- step 63 (peeled; dummy K prefetch wraps to 0) ----
    ATTN_STEP(63, 1, Kn0, Kn1, Vc, Kc0, Kc1, Vn);

    // ---- epilogue step: PV_63 from buf1, V(63) ----
    {
        const unsigned int* rb = smemw + khw + 1024;
        s8v pa0 = (cj == 0) ? ppv : *(const s8v*)(rb + rdo0);
        s8v pa1 = (cj == 1) ? ppv : *(const s8v*)(rb + rdo1);
        s8v pa2 = (cj == 2) ? ppv : *(const s8v*)(rb + rdo2);
        s8v pa3 = (cj == 3) ? ppv : *(const s8v*)(rb + rdo3);
        #pragma unroll
        for (int ct = 0; ct < 4; ct++) {
            O[0][ct] = __builtin_amdgcn_mfma_f32_16x16x32_bf16(Vn[ct], pa0, O[0][ct], 0, 0, 0);
            O[1][ct] = __builtin_amdgcn_mfma_f32_16x16x32_bf16(Vn[ct], pa1, O[1][ct], 0, 0, 0);
            O[2][ct] = __builtin_amdgcn_mfma_f32_16x16x32_bf16(Vn[ct], pa2, O[2][ct], 0, 0, 0);
            O[3][ct] = __builtin_amdgcn_mfma_f32_16x16x32_bf16(Vn[ct], pa3, O[3][ct], 0, 0, 0);
        }
    }

    // full row-sum for (rt=cj, kh): reduce over quads
    lsum += __shfl_xor(lsum, 16);
    lsum += __shfl_xor(lsum, 32);

    __syncthreads();   // drain all P reads; safe to alias smem as epilogue bufs

    float (*ldsO)[64][68] = (float (*)[64][68])smem;          // [cj][lane][16 f4v + pad]
    float* ldsL = (float*)(smem + 69632);                     // [kh][rt][16]

    if (quad == 0) ldsL[kh * 64 + cj * 16 + l16] = lsum;
    if (kh == 1) {
        #pragma unroll
        for (int rt = 0; rt < 4; rt++)
            #pragma unroll
            for (int ct = 0; ct < 4; ct++)
                *(f4v*)&ldsO[cj][lane][(rt * 4 + ct) * 4] = O[rt][ct];
    }
    __syncthreads();

    if (kh == 0) {
        float g = gamma[0];
        float rinv[4];
        #pragma unroll
        for (int rt = 0; rt < 4; rt++)
            rinv[rt] = g / (ldsL[rt * 16 + l16] + ldsL[64 + rt * 16 + l16]);
        #pragma unroll
        for (int rt = 0; rt < 4; rt++) {
            #pragma unroll
            for (int ct = 0; ct < 4; ct++) {
                f4v o2 = *(const f4v*)&ldsO[cj][lane][(rt * 4 + ct) * 4];
                #pragma unroll
                for (int r = 0; r < 4; r++) {
                    int ch = cj * 64 + ct * 16 + quad * 4 + r;
                    out[((size_t)b * CIN + ch) * NPIX + rowbase + rt * 16 + l16] =
                        (O[rt][ct][r] + o2[r]) * rinv[rt];
                }
            }
        }
    }
}

// ---------------------------------------------------------------------------
extern "C" void kernel_launch(void* const* d_in, const int* in_sizes, int n_in,
                              void* d_out, int out_size, void* d_ws, size_t ws_size,
                              hipStream_t stream) {
    const float* x     = (const float*)d_in[0];
    const float* Wq    = (const float*)d_in[1];
    const float* bq    = (const float*)d_in[2];
    const float* Wk    = (const float*)d_in[3];
    const float* bk    = (const float*)d_in[4];
    const float* Wv    = (const float*)d_in[5];
    const float* bv    = (const float*)d_in[6];
    const float* gamma = (const float*)d_in[7];
    float* out = (float*)d_out;

    char* p = (char*)d_ws;
    unsigned short* xT   = (unsigned short*)p; p += (size_t)4 * NPIX * CIN * 2;   // 8 MB
    unsigned short* Qb   = (unsigned short*)p; p += (size_t)4 * NPIX * DQK * 2;   // 1 MB
    unsigned short* Kb   = (unsigned short*)p; p += (size_t)4 * NPIX * DQK * 2;   // 1 MB
    unsigned short* Vt   = (unsigned short*)p; p += (size_t)4 * CIN * NPIX * 2;   // 8 MB
    unsigned short* Wall = (unsigned short*)p; p += (size_t)320 * 256 * 2;
    float*          ball = (float*)p;          p += (size_t)320 * 4;

    wcast_kernel<<<320, 256, 0, stream>>>(Wq, bq, Wk, bk, Wv, bv, Wall, ball);
    tcast_kernel<<<1024, 256, 0, stream>>>(x, xT);
    proj_kernel<<<256, 256, 0, stream>>>(xT, Wall, ball, Qb, Kb, Vt);
    attn_kernel<<<256, 512, 0, stream>>>(Qb, Kb, Vt, gamma, out);
}